// Round 4
// baseline (296.584 us; speedup 1.0000x reference)
//
#include <hip/hip_runtime.h>

typedef unsigned short u16;
typedef __bf16 bf16x8 __attribute__((ext_vector_type(8)));
typedef float f32x4 __attribute__((ext_vector_type(4)));

__device__ __forceinline__ float b2f(u16 x) {
    union { float f; unsigned u; } v; v.u = ((unsigned)x) << 16; return v.f;
}
__device__ __forceinline__ u16 f2b(float f) {
    union { float f; unsigned u; } v; v.f = f;
    unsigned u = v.u;
    return (u16)((u + 0x7FFFu + ((u >> 16) & 1u)) >> 16);
}
// pack two f32 -> two truncated bf16 in one dword (lo=a, hi=b)
__device__ __forceinline__ unsigned pk2(float a, float b) {
    unsigned ua = __float_as_uint(a), ub = __float_as_uint(b);
    return (ub & 0xFFFF0000u) | (ua >> 16);
}
__device__ __forceinline__ f32x4 mfma_16x16x32(bf16x8 a, bf16x8 b, f32x4 c) {
    return __builtin_amdgcn_mfma_f32_16x16x32_bf16(a, b, c, 0, 0, 0);
}
// async global->LDS, 16B per lane. LDS dest = wave-uniform base + lane*16.
__device__ __forceinline__ void gld_lds16(const u16* g, u16* l) {
    __builtin_amdgcn_global_load_lds(
        (const __attribute__((address_space(1))) unsigned int*)g,
        (__attribute__((address_space(3))) unsigned int*)l,
        16, 0, 0);
}

#define VSTRIDE 2080
#define LOG2E 1.44269504f

// ---------------------------------------------------------------------------
// prep: inputs f32->bf16 [0,4096); W_in T+cvt [4096,7168); W_out T+cvt [7168,8192)
// ---------------------------------------------------------------------------
__global__ __launch_bounds__(256) void prep(const float* __restrict__ inputs,
                                            u16* __restrict__ inB,
                                            const float* __restrict__ W_in,
                                            u16* __restrict__ WtB,
                                            const float* __restrict__ W_out,
                                            u16* __restrict__ WotB) {
    __shared__ float T[32][33];
    const int bx = blockIdx.x;
    if (bx < 4096) {
        int i = (bx * 256 + threadIdx.x) * 4;
        float4 v = *(const float4*)(inputs + i);
        ushort4 o;
        o.x = f2b(v.x); o.y = f2b(v.y); o.z = f2b(v.z); o.w = f2b(v.w);
        *(ushort4*)(inB + i) = o;
        return;
    }
    const float* src; u16* dst; int R, C, c0, r0;
    if (bx < 7168) {
        int t = bx - 4096; src = W_in; dst = WtB; R = 1024; C = 3072;
        c0 = (t % 96) * 32; r0 = (t / 96) * 32;
    } else {
        int t = bx - 7168; src = W_out; dst = WotB; R = 1024; C = 1024;
        c0 = (t % 32) * 32; r0 = (t / 32) * 32;
    }
    int tr = threadIdx.x >> 5, tc = threadIdx.x & 31;
#pragma unroll
    for (int p = 0; p < 4; ++p)
        T[tr + p * 8][tc] = src[(size_t)(r0 + tr + p * 8) * C + c0 + tc];
    __syncthreads();
#pragma unroll
    for (int p = 0; p < 4; ++p)
        dst[(size_t)(c0 + tr + p * 8) * R + r0 + tc] = f2b(T[tc][tr + p * 8]);
}

// ---------------------------------------------------------------------------
// GEMM (m97 structure): C[M,N] = A[M,K] * Bt[N,K]^T. bf16 in, f32 accum.
// ---------------------------------------------------------------------------
template <bool F32OUT>
__global__ __launch_bounds__(256) void gemm_tn(const u16* __restrict__ A,
                                               const u16* __restrict__ Bt,
                                               void* __restrict__ Cv,
                                               int M, int N, int K) {
    __shared__ u16 As[128 * 32];
    __shared__ u16 Bs[128 * 32];
    const int tid = threadIdx.x;
    const int m0 = blockIdx.y * 128;
    const int n0 = blockIdx.x * 128;
    const int w = tid >> 6, lane = tid & 63;
    const int col16 = lane & 15, quad = lane >> 4;
    const int wm = (w >> 1) * 64, wn = (w & 1) * 64;
    const int srow = (lane >> 2), sseg = (lane & 3) * 8;

    f32x4 acc[4][4];
#pragma unroll
    for (int i = 0; i < 4; ++i)
#pragma unroll
        for (int j = 0; j < 4; ++j) acc[i][j] = (f32x4){0.f, 0.f, 0.f, 0.f};

    for (int kt = 0; kt < K; kt += 32) {
#pragma unroll
        for (int cc = 0; cc < 2; ++cc) {
            int c = w * 2 + cc;
            int row = c * 16 + srow;
            gld_lds16(A + (size_t)(m0 + row) * K + kt + sseg, &As[c * 512 + lane * 8]);
            gld_lds16(Bt + (size_t)(n0 + row) * K + kt + sseg, &Bs[c * 512 + lane * 8]);
        }
        __syncthreads();

        bf16x8 af[4], bfr[4];
#pragma unroll
        for (int i = 0; i < 4; ++i)
            af[i] = *(const bf16x8*)&As[(wm + i * 16 + col16) * 32 + quad * 8];
#pragma unroll
        for (int j = 0; j < 4; ++j)
            bfr[j] = *(const bf16x8*)&Bs[(wn + j * 16 + col16) * 32 + quad * 8];
#pragma unroll
        for (int i = 0; i < 4; ++i)
#pragma unroll
            for (int j = 0; j < 4; ++j)
                acc[i][j] = mfma_16x16x32(af[i], bfr[j], acc[i][j]);
        __syncthreads();
    }

#pragma unroll
    for (int i = 0; i < 4; ++i) {
#pragma unroll
        for (int r = 0; r < 4; ++r) {
            int m = m0 + wm + i * 16 + quad * 4 + r;
            if (F32OUT) {
                float* Crow = (float*)Cv + (size_t)m * N + n0 + wn;
#pragma unroll
                for (int j = 0; j < 4; ++j)
                    Crow[j * 16 + col16] = acc[i][j][r];
            } else {
                u16* Crow = (u16*)Cv + (size_t)m * N + n0 + wn;
#pragma unroll
                for (int j = 0; j < 4; ++j)
                    Crow[j * 16 + col16] = f2b(acc[i][j][r]);
            }
        }
    }
}

// ---------------------------------------------------------------------------
// Fused rope + v_transpose. blocks [0,1024): RoPE (q scaled log2e/8);
// blocks [1024,3072): V transpose into Vt [BH][64][VSTRIDE].
// ---------------------------------------------------------------------------
__global__ __launch_bounds__(256) void rope_vt(const u16* __restrict__ qkv,
                                               const int* __restrict__ segpos,
                                               u16* __restrict__ Qh,
                                               u16* __restrict__ Kh,
                                               u16* __restrict__ Vt) {
    __shared__ u16 T[32][72];
    const int bx = blockIdx.x;
    if (bx < 1024) {
        int t = bx * 256 + threadIdx.x;
        int seg = t & 3;
        int h = (t >> 2) & 15;
        int row = t >> 6;
        float pos = (float)segpos[row];
        const u16* base = qkv + (size_t)row * 3072 + h * 192 + seg * 8;
        union { uint4 u; u16 s[8]; } q1, q2, k1, k2, oq1, oq2, ok1, ok2;
        q1.u = *(const uint4*)(base);
        q2.u = *(const uint4*)(base + 32);
        k1.u = *(const uint4*)(base + 64);
        k2.u = *(const uint4*)(base + 96);
        const float qs = 0.125f * LOG2E;
#pragma unroll
        for (int j = 0; j < 8; ++j) {
            int d = seg * 8 + j;
            float inv_freq = __expf(-(float)d * (9.210340371976184f / 32.0f));
            float ang = pos * inv_freq;
            float c = __cosf(ang), s = __sinf(ang);
            float a1 = b2f(q1.s[j]), a2 = b2f(q2.s[j]);
            float b1 = b2f(k1.s[j]), b2v = b2f(k2.s[j]);
            oq1.s[j] = f2b((a1 * c - a2 * s) * qs);
            oq2.s[j] = f2b((a1 * s + a2 * c) * qs);
            ok1.s[j] = f2b(b1 * c - b2v * s);
            ok2.s[j] = f2b(b1 * s + b2v * c);
        }
        int b = row >> 11, srow = row & 2047;
        size_t idx = ((size_t)(b * 16 + h) * 2048 + srow) * 64 + seg * 8;
        *(uint4*)&Qh[idx]      = oq1.u;
        *(uint4*)&Qh[idx + 32] = oq2.u;
        *(uint4*)&Kh[idx]      = ok1.u;
        *(uint4*)&Kh[idx + 32] = ok2.u;
        return;
    }
    int bxx = bx - 1024;
    int s0 = (bxx & 63) * 32;
    int bh = bxx >> 6;
    int b = bh >> 4, h = bh & 15;
    int t = threadIdx.x;
    {
        int r = t >> 3, seg = t & 7;
        const u16* src = qkv + (size_t)(b * 2048 + s0 + r) * 3072 + h * 192 + 128 + seg * 8;
        *(uint4*)&T[r][seg * 8] = *(const uint4*)src;
    }
    __syncthreads();
    {
        int d = t >> 2, ss = (t & 3) * 8;
        union { uint4 u; u16 s[8]; } w;
#pragma unroll
        for (int j = 0; j < 8; ++j) w.s[j] = T[ss + j][d];
        *(uint4*)(Vt + (size_t)bh * 64 * VSTRIDE + (size_t)d * VSTRIDE + s0 + ss) = w.u;
    }
}

// ---------------------------------------------------------------------------
// Flash attention v11: v9 compute (2-phase gld_lds pipeline, XOR swizzle),
// restructured for 4 blocks/CU:
//  - Ps halved to [4][16*64] via t-sequential PV (V fragments in registers,
//    loaded once); lred aliased into Ps => LDS = 40960B exactly (4 blocks/CU).
//  - finer near-uniform split-K: units of <=11 chunks, 32 units/bh,
//    grid 1024 = 4 blocks/CU all-resident; per-bh slot rotation balances
//    per-CU load. 27 f32 partial slots/bh -> attn_reduce.
// ---------------------------------------------------------------------------
#define FIXED_M2 34.6246561f    // 24 * log2(e)

// slot tables (per bh, 32 slots), descending tile order.
// STQ: q-tile; SC0: first chunk; SNC: #chunks; SPS: partial slot (-1=direct)
__device__ const int STQ[32] = {15,15,15, 14,14,14, 13,13,13, 12,12,12, 11,11,11,
                                10,10, 9,9, 8,8, 7,7, 6,6, 5,5, 4, 3, 2, 1, 0};
__device__ const int SC0[32] = {0,11,22, 0,10,20, 0,10,19, 0,9,18, 0,8,16,
                                0,11, 0,10, 0,9, 0,8, 0,7, 0,6, 0, 0, 0, 0, 0};
__device__ const int SNC[32] = {11,11,10, 10,10,10, 10,9,9, 9,9,8, 8,8,8,
                                11,11, 10,10, 9,9, 8,8, 7,7, 6,6, 10, 8, 6, 4, 2};
__device__ const int SPS[32] = {0,1,2, 3,4,5, 6,7,8, 9,10,11, 12,13,14,
                                15,16, 17,18, 19,20, 21,22, 23,24, 25,26, -1,-1,-1,-1,-1};
// reduce tables: 11 multi-unit tiles (tq 5..15)
__device__ const int RTQ[11] = {15,14,13,12,11,10,9,8,7,6,5};
__device__ const int RB[11]  = {0,3,6,9,12,15,17,19,21,23,25};
__device__ const int RN[11]  = {3,3,3,3,3,2,2,2,2,2,2};

__global__ __launch_bounds__(256, 4) void attn_v11(const u16* __restrict__ Qh,
                                                   const u16* __restrict__ Kh,
                                                   const u16* __restrict__ Vt,
                                                   u16* __restrict__ X,
                                                   float* __restrict__ Opart,
                                                   float* __restrict__ Lpart) {
    __shared__ u16 Ks[2][64 * 64];   // [buf][k-row][64 d]  (8KB/buf)
    __shared__ u16 Vs[2][64 * 64];   // [buf][d-row][64 k]  (8KB/buf)
    __shared__ u16 Ps[4][16 * 64];   // wave-private P [16 q][64 k], swizzled (8KB)
                                     // (front 128B/wave reused as lred after loop)
    const int tid = threadIdx.x;
    const int w = tid >> 6, lane = tid & 63;
    const int col16 = lane & 15, quad = lane >> 4;
    // XCD-aware swizzle: 1024 = 8 XCD x 128; each XCD owns 4 bh.
    // per-bh slot rotation (+8) spreads unit sizes across CUs.
    const int raw = blockIdx.x;
    const int bsw = (raw & 7) * 128 + (raw >> 3);
    const int bh = bsw >> 5;
    const int slot = ((bsw & 31) + bh * 8) & 31;
    const int tq = STQ[slot];
    const int c0 = SC0[slot];
    const int nc = SNC[slot];
    const int ps = SPS[slot];
    const int q0 = tq * 128 + w * 32;
    const u16* Qp = Qh + (size_t)bh * 2048 * 64;
    const u16* Kp = Kh + (size_t)bh * 2048 * 64;
    const u16* Vp = Vt + (size_t)bh * 64 * VSTRIDE;
    u16* Pw = Ps[w];
    const int swz = (col16 & 7) << 3;      // row-XOR for all LDS tiles (u16 units)

    // Q fragments (used as B-operand of K*Q^T -- identical lane data)
    bf16x8 qa[2][2];
#pragma unroll
    for (int t = 0; t < 2; ++t)
#pragma unroll
        for (int hf = 0; hf < 2; ++hf)
            qa[t][hf] = *(const bf16x8*)&Qp[(size_t)(q0 + t * 16 + col16) * 64 + hf * 32 + quad * 8];

    float l_acc[2] = {0.f, 0.f};
    f32x4 o[2][4];
#pragma unroll
    for (int t = 0; t < 2; ++t)
#pragma unroll
        for (int f = 0; f < 4; ++f) o[t][f] = (f32x4){0.f, 0.f, 0.f, 0.f};

    // staging decomposition: each gld_lds covers 8 rows x 128B; lane = r*8+s.
    // swizzled granule: global slot = s ^ r  (involution; read applies same XOR)
    const int sr = lane >> 3;              // row within instr (0..7)
    const int sg = ((lane & 7) ^ sr) * 8;  // pre-swizzled 16B granule (u16 units)

    // ---- prologue: stage chunk c0 into buf 0 (4 instrs/wave: 2 K + 2 V) ----
    {
        const int k0 = c0 * 64;
#pragma unroll
        for (int i = 0; i < 2; ++i) {
            int c = w * 2 + i;
            gld_lds16(Kp + (size_t)(k0 + c * 8 + sr) * 64 + sg, &Ks[0][c * 512 + lane * 8]);
        }
#pragma unroll
        for (int i = 0; i < 2; ++i) {
            int c = w * 2 + i;
            gld_lds16(Vp + (size_t)(c * 8 + sr) * VSTRIDE + k0 + sg, &Vs[0][c * 512 + lane * 8]);
        }
    }

    for (int ci = 0; ci < nc; ++ci) {
        const int cur = ci & 1;
        const u16* KsC = Ks[cur];
        const u16* VsC = Vs[cur];

        // ---- issue next chunk's stage into the other buffer ----
        if (ci + 1 < nc) {
            const int k0n = (c0 + ci + 1) * 64;
            u16* Kd = Ks[cur ^ 1];
            u16* Vd = Vs[cur ^ 1];
#pragma unroll
            for (int i = 0; i < 2; ++i) {
                int c = w * 2 + i;
                gld_lds16(Kp + (size_t)(k0n + c * 8 + sr) * 64 + sg, Kd + c * 512 + lane * 8);
            }
#pragma unroll
            for (int i = 0; i < 2; ++i) {
                int c = w * 2 + i;
                gld_lds16(Vp + (size_t)(c * 8 + sr) * VSTRIDE + k0n + sg, Vd + c * 512 + lane * 8);
            }
            // wait only for CURRENT chunk's 4 loads; next chunk's 4 stay in flight
            asm volatile("s_waitcnt vmcnt(4)" ::: "memory");
        } else {
            asm volatile("s_waitcnt vmcnt(0)" ::: "memory");
        }
        asm volatile("s_barrier" ::: "memory");

        const int k0 = (c0 + ci) * 64;

        // ---- K*Q^T -> S^T ----
        f32x4 s[2][4];
#pragma unroll
        for (int t = 0; t < 2; ++t)
#pragma unroll
            for (int kt = 0; kt < 4; ++kt) s[t][kt] = (f32x4){0.f, 0.f, 0.f, 0.f};
#pragma unroll
        for (int kt = 0; kt < 4; ++kt) {
            const u16* kb = &KsC[(kt * 16 + col16) * 64];
            bf16x8 kf0 = *(const bf16x8*)&kb[(quad * 8) ^ swz];
            bf16x8 kf1 = *(const bf16x8*)&kb[(32 + quad * 8) ^ swz];
            s[0][kt] = mfma_16x16x32(kf0, qa[0][0], s[0][kt]);
            s[0][kt] = mfma_16x16x32(kf1, qa[0][1], s[0][kt]);
            s[1][kt] = mfma_16x16x32(kf0, qa[1][0], s[1][kt]);
            s[1][kt] = mfma_16x16x32(kf1, qa[1][1], s[1][kt]);
        }

        const bool domask = (k0 + 63 > q0);

        // ---- t = 0: softmax -> P tile -> PV ----
        {
            const int qg = q0 + col16;
            float rs = 0.f;
#pragma unroll
            for (int kt = 0; kt < 4; ++kt) {
                float p[4];
#pragma unroll
                for (int r = 0; r < 4; ++r) {
                    float sv = s[0][kt][r];
                    if (domask && (k0 + kt * 16 + quad * 4 + r > qg)) sv = -1e30f;
                    p[r] = __builtin_amdgcn_exp2f(sv - FIXED_M2);
                    rs += p[r];
                }
                unsigned* prow = (unsigned*)&Pw[col16 * 64 + ((kt * 16 + quad * 4) ^ swz)];
                prow[0] = pk2(p[0], p[1]);
                prow[1] = pk2(p[2], p[3]);
            }
            l_acc[0] += rs;
        }
        // V fragments to registers (live across both t's PV)
        bf16x8 vf[2][4];
#pragma unroll
        for (int ss = 0; ss < 2; ++ss)
#pragma unroll
            for (int f = 0; f < 4; ++f)
                vf[ss][f] = *(const bf16x8*)&VsC[(f * 16 + col16) * 64 + ((ss * 32 + quad * 8) ^ swz)];
        asm volatile("s_waitcnt lgkmcnt(0)" ::: "memory");  // P writes + vf done
#pragma unroll
        for (int ss = 0; ss < 2; ++ss) {
            const int ko = (ss * 32 + quad * 8) ^ swz;
            bf16x8 pf = *(const bf16x8*)&Pw[col16 * 64 + ko];
#pragma unroll
            for (int f = 0; f < 4; ++f)
                o[0][f] = mfma_16x16x32(pf, vf[ss][f], o[0][f]);
        }

        // ---- t = 1: softmax -> P tile (overwrite) -> PV ----
        {
            const int qg = q0 + 16 + col16;
            float rs = 0.f;
#pragma unroll
            for (int kt = 0; kt < 4; ++kt) {
                float p[4];
#pragma unroll
                for (int r = 0; r < 4; ++r) {
                    float sv = s[1][kt][r];
                    if (domask && (k0 + kt * 16 + quad * 4 + r > qg)) sv = -1e30f;
                    p[r] = __builtin_amdgcn_exp2f(sv - FIXED_M2);
                    rs += p[r];
                }
                unsigned* prow = (unsigned*)&Pw[col16 * 64 + ((kt * 16 + quad * 4) ^ swz)];
                prow[0] = pk2(p[0], p[1]);
                prow[1] = pk2(p[2], p[3]);
            }
            l_acc[1] += rs;
        }
        asm volatile("s_waitcnt lgkmcnt(0)" ::: "memory");  // P writes -> reads
#pragma unroll
        for (int ss = 0; ss < 2; ++ss) {
            const int ko = (ss * 32 + quad * 8) ^ swz;
            bf16x8 pf = *(const bf16x8*)&Pw[col16 * 64 + ko];
#pragma unroll
            for (int f = 0; f < 4; ++f)
                o[1][f] = mfma_16x16x32(pf, vf[ss][f], o[1][f]);
        }

        // all LDS reads of buf[cur] complete before next iteration's stage
        asm volatile("s_waitcnt lgkmcnt(0)" ::: "memory");
        asm volatile("s_barrier" ::: "memory");
    }

    // ---- l reduction across quads (butterfly -> every lane has row total) ----
    float* lredw = (float*)Pw;   // alias: P tile dead after loop
    float lt[2];
#pragma unroll
    for (int t = 0; t < 2; ++t) {
        float l = l_acc[t];
        l += __shfl_xor(l, 16);
        l += __shfl_xor(l, 32);
        lt[t] = l;
        if (quad == 0) lredw[t * 16 + col16] = l;
    }
    asm volatile("s_waitcnt lgkmcnt(0)" ::: "memory");

    if (ps >= 0) {
        // ---- partial epilogue: raw O (no divide) + l to workspace ----
        const int pg = bh * 27 + ps;
        float* Op = Opart + ((size_t)pg * 128 + w * 32) * 64;
#pragma unroll
        for (int t = 0; t < 2; ++t) {
#pragma unroll
            for (int r = 0; r < 4; ++r) {
                float* Crow = Op + (t * 16 + quad * 4 + r) * 64;
#pragma unroll
                for (int f = 0; f < 4; ++f)
                    Crow[f * 16 + col16] = o[t][f][r];
            }
        }
        if (quad == 0) {
            float* Lp = Lpart + (size_t)pg * 128 + w * 32;
#pragma unroll
            for (int t = 0; t < 2; ++t) Lp[t * 16 + col16] = lt[t];
        }
        return;
    }

    // ---- direct epilogue (single-unit tile): divide and write X ----
    const int b = bh >> 4, h = bh & 15;
#pragma unroll
    for (int t = 0; t < 2; ++t) {
#pragma unroll
        for (int r = 0; r < 4; ++r) {
            float inv = 1.0f / lredw[t * 16 + quad * 4 + r];
            int srow = q0 + t * 16 + quad * 4 + r;
            u16* Xp = X + ((size_t)(b * 2048 + srow)) * 1024 + h * 64;
#pragma unroll
            for (int f = 0; f < 4; ++f)
                Xp[f * 16 + col16] = f2b(o[t][f][r] * inv);
        }
    }
}

// ---------------------------------------------------------------------------
// attn_reduce: combine 2-3 partials per (bh, tq in 5..15): X = (sum O)/(sum l)
// ---------------------------------------------------------------------------
__global__ __launch_bounds__(256) void attn_reduce(const float* __restrict__ Opart,
                                                   const float* __restrict__ Lpart,
                                                   u16* __restrict__ X) {
    const int bh = blockIdx.x;           // 0..31
    const int ti = blockIdx.y;           // 0..10
    const int tq = RTQ[ti];
    const int np = RN[ti];
    const int base = bh * 27 + RB[ti];
    const int tid = threadIdx.x;
    const int b = bh >> 4, h = bh & 15;
#pragma unroll
    for (int i = 0; i < 8; ++i) {
        int e4 = i * 256 + tid;          // float4 index within 128x64 tile
        int q = e4 >> 4, d0 = (e4 & 15) * 4;
        float4 a = ((const float4*)Opart)[(size_t)base * 2048 + e4];
        float l = Lpart[(size_t)base * 128 + q];
        for (int u = 1; u < np; ++u) {
            float4 c = ((const float4*)Opart)[(size_t)(base + u) * 2048 + e4];
            a.x += c.x; a.y += c.y; a.z += c.z; a.w += c.w;
            l += Lpart[(size_t)(base + u) * 128 + q];
        }
        float inv = 1.0f / l;
        ushort4 ov;
        ov.x = f2b(a.x * inv); ov.y = f2b(a.y * inv);
        ov.z = f2b(a.z * inv); ov.w = f2b(a.w * inv);
        *(ushort4*)&X[((size_t)(b * 2048 + tq * 128 + q)) * 1024 + h * 64 + d0] = ov;
    }
}

// ---------------------------------------------------------------------------
// launch
// ---------------------------------------------------------------------------
extern "C" void kernel_launch(void* const* d_in, const int* in_sizes, int n_in,
                              void* d_out, int out_size, void* d_ws, size_t ws_size,
                              hipStream_t stream) {
    const float* inputs = (const float*)d_in[0];
    const int* segpos   = (const int*)d_in[1];
    const float* W_in   = (const float*)d_in[3];
    const float* W_out  = (const float*)d_in[4];
    float* out = (float*)d_out;

    u16* ws = (u16*)d_ws;
    u16* qkv   = ws;                               // 4096*3072 bf16
    u16* x     = qkv;                              // alias (qkv dead after rope_vt)
    u16* inB   = qkv + 12582912 + 512;
    u16* WtB   = inB + 4194304 + 512;              // W_in^T  [3072][1024]
    u16* WotB  = WtB + 3145728 + 512;              // W_out^T [1024][1024]
    u16* Qh    = WotB + 1048576 + 512;             // [BH][S][64]
    u16* Kh    = Qh + 4194304 + 512;
    u16* Vt    = Kh + 4194304 + 512;               // [BH][64][VSTRIDE]
    // split-K partials: region [X_end, WotB) is dead during attn.
    // X = 4.19M u16; Opart: 864 slots x 128 x 64 f32 = 14,155,776 u16;
    // Lpart: 864 x 128 f32 = 221,184 u16; end = 18,571,776 < 19,924,480. OK.
    float* Opart = (float*)(ws + 4194816);
    float* Lpart = (float*)(ws + 4194816 + 14155776);

    prep<<<dim3(8192), 256, 0, stream>>>(inputs, inB, W_in, WtB, W_out, WotB);
    gemm_tn<false><<<dim3(24, 32), 256, 0, stream>>>(inB, WtB, qkv, 4096, 3072, 1024);
    rope_vt<<<dim3(3072), 256, 0, stream>>>(qkv, segpos, Qh, Kh, Vt);
    attn_v11<<<dim3(1024), 256, 0, stream>>>(Qh, Kh, Vt, x, Opart, Lpart);
    attn_reduce<<<dim3(32, 11), 256, 0, stream>>>(Opart, Lpart, x);
    gemm_tn<true><<<dim3(8, 32), 256, 0, stream>>>(x, WotB, out, 4096, 1024, 1024);
}

// Round 5
// 219.773 us; speedup vs baseline: 1.3495x; 1.3495x over previous
//
#include <hip/hip_runtime.h>

typedef unsigned short u16;
typedef __bf16 bf16x8 __attribute__((ext_vector_type(8)));
typedef float f32x4 __attribute__((ext_vector_type(4)));

__device__ __forceinline__ float b2f(u16 x) {
    union { float f; unsigned u; } v; v.u = ((unsigned)x) << 16; return v.f;
}
__device__ __forceinline__ u16 f2b(float f) {
    union { float f; unsigned u; } v; v.f = f;
    unsigned u = v.u;
    return (u16)((u + 0x7FFFu + ((u >> 16) & 1u)) >> 16);
}
// pack two f32 -> two truncated bf16 in one dword (lo=a, hi=b)
__device__ __forceinline__ unsigned pk2(float a, float b) {
    unsigned ua = __float_as_uint(a), ub = __float_as_uint(b);
    return (ub & 0xFFFF0000u) | (ua >> 16);
}
__device__ __forceinline__ f32x4 mfma_16x16x32(bf16x8 a, bf16x8 b, f32x4 c) {
    return __builtin_amdgcn_mfma_f32_16x16x32_bf16(a, b, c, 0, 0, 0);
}
// async global->LDS, 16B per lane. LDS dest = wave-uniform base + lane*16.
__device__ __forceinline__ void gld_lds16(const u16* g, u16* l) {
    __builtin_amdgcn_global_load_lds(
        (const __attribute__((address_space(1))) unsigned int*)g,
        (__attribute__((address_space(3))) unsigned int*)l,
        16, 0, 0);
}

#define VSTRIDE 2080
#define LOG2E 1.44269504f

// ---------------------------------------------------------------------------
// prep: inputs f32->bf16 [0,4096); W_in T+cvt [4096,7168); W_out T+cvt [7168,8192)
// ---------------------------------------------------------------------------
__global__ __launch_bounds__(256) void prep(const float* __restrict__ inputs,
                                            u16* __restrict__ inB,
                                            const float* __restrict__ W_in,
                                            u16* __restrict__ WtB,
                                            const float* __restrict__ W_out,
                                            u16* __restrict__ WotB) {
    __shared__ float T[32][33];
    const int bx = blockIdx.x;
    if (bx < 4096) {
        int i = (bx * 256 + threadIdx.x) * 4;
        float4 v = *(const float4*)(inputs + i);
        ushort4 o;
        o.x = f2b(v.x); o.y = f2b(v.y); o.z = f2b(v.z); o.w = f2b(v.w);
        *(ushort4*)(inB + i) = o;
        return;
    }
    const float* src; u16* dst; int R, C, c0, r0;
    if (bx < 7168) {
        int t = bx - 4096; src = W_in; dst = WtB; R = 1024; C = 3072;
        c0 = (t % 96) * 32; r0 = (t / 96) * 32;
    } else {
        int t = bx - 7168; src = W_out; dst = WotB; R = 1024; C = 1024;
        c0 = (t % 32) * 32; r0 = (t / 32) * 32;
    }
    int tr = threadIdx.x >> 5, tc = threadIdx.x & 31;
#pragma unroll
    for (int p = 0; p < 4; ++p)
        T[tr + p * 8][tc] = src[(size_t)(r0 + tr + p * 8) * C + c0 + tc];
    __syncthreads();
#pragma unroll
    for (int p = 0; p < 4; ++p)
        dst[(size_t)(c0 + tr + p * 8) * R + r0 + tc] = f2b(T[tc][tr + p * 8]);
}

// ---------------------------------------------------------------------------
// GEMM (m97 structure): C[M,N] = A[M,K] * Bt[N,K]^T. bf16 in, f32 accum.
// ---------------------------------------------------------------------------
template <bool F32OUT>
__global__ __launch_bounds__(256) void gemm_tn(const u16* __restrict__ A,
                                               const u16* __restrict__ Bt,
                                               void* __restrict__ Cv,
                                               int M, int N, int K) {
    __shared__ u16 As[128 * 32];
    __shared__ u16 Bs[128 * 32];
    const int tid = threadIdx.x;
    const int m0 = blockIdx.y * 128;
    const int n0 = blockIdx.x * 128;
    const int w = tid >> 6, lane = tid & 63;
    const int col16 = lane & 15, quad = lane >> 4;
    const int wm = (w >> 1) * 64, wn = (w & 1) * 64;
    const int srow = (lane >> 2), sseg = (lane & 3) * 8;

    f32x4 acc[4][4];
#pragma unroll
    for (int i = 0; i < 4; ++i)
#pragma unroll
        for (int j = 0; j < 4; ++j) acc[i][j] = (f32x4){0.f, 0.f, 0.f, 0.f};

    for (int kt = 0; kt < K; kt += 32) {
#pragma unroll
        for (int cc = 0; cc < 2; ++cc) {
            int c = w * 2 + cc;
            int row = c * 16 + srow;
            gld_lds16(A + (size_t)(m0 + row) * K + kt + sseg, &As[c * 512 + lane * 8]);
            gld_lds16(Bt + (size_t)(n0 + row) * K + kt + sseg, &Bs[c * 512 + lane * 8]);
        }
        __syncthreads();

        bf16x8 af[4], bfr[4];
#pragma unroll
        for (int i = 0; i < 4; ++i)
            af[i] = *(const bf16x8*)&As[(wm + i * 16 + col16) * 32 + quad * 8];
#pragma unroll
        for (int j = 0; j < 4; ++j)
            bfr[j] = *(const bf16x8*)&Bs[(wn + j * 16 + col16) * 32 + quad * 8];
#pragma unroll
        for (int i = 0; i < 4; ++i)
#pragma unroll
            for (int j = 0; j < 4; ++j)
                acc[i][j] = mfma_16x16x32(af[i], bfr[j], acc[i][j]);
        __syncthreads();
    }

#pragma unroll
    for (int i = 0; i < 4; ++i) {
#pragma unroll
        for (int r = 0; r < 4; ++r) {
            int m = m0 + wm + i * 16 + quad * 4 + r;
            if (F32OUT) {
                float* Crow = (float*)Cv + (size_t)m * N + n0 + wn;
#pragma unroll
                for (int j = 0; j < 4; ++j)
                    Crow[j * 16 + col16] = acc[i][j][r];
            } else {
                u16* Crow = (u16*)Cv + (size_t)m * N + n0 + wn;
#pragma unroll
                for (int j = 0; j < 4; ++j)
                    Crow[j * 16 + col16] = f2b(acc[i][j][r]);
            }
        }
    }
}

// ---------------------------------------------------------------------------
// Fused rope + v_transpose. blocks [0,1024): RoPE (q scaled log2e/8);
// blocks [1024,3072): V transpose into Vt [BH][64][VSTRIDE].
// ---------------------------------------------------------------------------
__global__ __launch_bounds__(256) void rope_vt(const u16* __restrict__ qkv,
                                               const int* __restrict__ segpos,
                                               u16* __restrict__ Qh,
                                               u16* __restrict__ Kh,
                                               u16* __restrict__ Vt) {
    __shared__ u16 T[32][72];
    const int bx = blockIdx.x;
    if (bx < 1024) {
        int t = bx * 256 + threadIdx.x;
        int seg = t & 3;
        int h = (t >> 2) & 15;
        int row = t >> 6;
        float pos = (float)segpos[row];
        const u16* base = qkv + (size_t)row * 3072 + h * 192 + seg * 8;
        union { uint4 u; u16 s[8]; } q1, q2, k1, k2, oq1, oq2, ok1, ok2;
        q1.u = *(const uint4*)(base);
        q2.u = *(const uint4*)(base + 32);
        k1.u = *(const uint4*)(base + 64);
        k2.u = *(const uint4*)(base + 96);
        const float qs = 0.125f * LOG2E;
#pragma unroll
        for (int j = 0; j < 8; ++j) {
            int d = seg * 8 + j;
            float inv_freq = __expf(-(float)d * (9.210340371976184f / 32.0f));
            float ang = pos * inv_freq;
            float c = __cosf(ang), s = __sinf(ang);
            float a1 = b2f(q1.s[j]), a2 = b2f(q2.s[j]);
            float b1 = b2f(k1.s[j]), b2v = b2f(k2.s[j]);
            oq1.s[j] = f2b((a1 * c - a2 * s) * qs);
            oq2.s[j] = f2b((a1 * s + a2 * c) * qs);
            ok1.s[j] = f2b(b1 * c - b2v * s);
            ok2.s[j] = f2b(b1 * s + b2v * c);
        }
        int b = row >> 11, srow = row & 2047;
        size_t idx = ((size_t)(b * 16 + h) * 2048 + srow) * 64 + seg * 8;
        *(uint4*)&Qh[idx]      = oq1.u;
        *(uint4*)&Qh[idx + 32] = oq2.u;
        *(uint4*)&Kh[idx]      = ok1.u;
        *(uint4*)&Kh[idx + 32] = ok2.u;
        return;
    }
    int bxx = bx - 1024;
    int s0 = (bxx & 63) * 32;
    int bh = bxx >> 6;
    int b = bh >> 4, h = bh & 15;
    int t = threadIdx.x;
    {
        int r = t >> 3, seg = t & 7;
        const u16* src = qkv + (size_t)(b * 2048 + s0 + r) * 3072 + h * 192 + 128 + seg * 8;
        *(uint4*)&T[r][seg * 8] = *(const uint4*)src;
    }
    __syncthreads();
    {
        int d = t >> 2, ss = (t & 3) * 8;
        union { uint4 u; u16 s[8]; } w;
#pragma unroll
        for (int j = 0; j < 8; ++j) w.s[j] = T[ss + j][d];
        *(uint4*)(Vt + (size_t)bh * 64 * VSTRIDE + (size_t)d * VSTRIDE + s0 + ss) = w.u;
    }
}

// ---------------------------------------------------------------------------
// Flash attention v12: v9's proven compute (2-phase gld_lds pipeline, XOR
// swizzle, vmcnt(4)), with occupancy raised to 4 blocks/CU the register-safe
// way:
//  - Ps halved to [4][16*64] via t-sequential softmax->PV; vf re-read from
//    LDS each pass (NOT hoisted -- v11's reg-pressure mistake); lred aliased
//    into the dead P tile => LDS = 40960B exactly (4 blocks/CU).
//  - plain __launch_bounds__(256): NO min-waves attr (v10/v11's (256,4) made
//    the allocator target 8 waves/EU -> VGPR 64 + ~470MB scratch spills).
//  - grid 1024 = 32 bh x 32 near-uniform units (<=11 chunks), all-resident;
//    per-bh slot rotation balances per-CU load; XCD-swizzled (4 bh/XCD).
// ---------------------------------------------------------------------------
#define FIXED_M2 34.6246561f    // 24 * log2(e)

// slot tables (per bh, 32 slots), descending tile order.
// STQ: q-tile; SC0: first chunk; SNC: #chunks; SPS: partial slot (-1=direct)
__device__ const int STQ[32] = {15,15,15, 14,14,14, 13,13,13, 12,12,12, 11,11,11,
                                10,10, 9,9, 8,8, 7,7, 6,6, 5,5, 4, 3, 2, 1, 0};
__device__ const int SC0[32] = {0,11,22, 0,10,20, 0,10,19, 0,9,18, 0,8,16,
                                0,11, 0,10, 0,9, 0,8, 0,7, 0,6, 0, 0, 0, 0, 0};
__device__ const int SNC[32] = {11,11,10, 10,10,10, 10,9,9, 9,9,8, 8,8,8,
                                11,11, 10,10, 9,9, 8,8, 7,7, 6,6, 10, 8, 6, 4, 2};
__device__ const int SPS[32] = {0,1,2, 3,4,5, 6,7,8, 9,10,11, 12,13,14,
                                15,16, 17,18, 19,20, 21,22, 23,24, 25,26, -1,-1,-1,-1,-1};
// reduce tables: 11 multi-unit tiles (tq 5..15)
__device__ const int RTQ[11] = {15,14,13,12,11,10,9,8,7,6,5};
__device__ const int RB[11]  = {0,3,6,9,12,15,17,19,21,23,25};
__device__ const int RN[11]  = {3,3,3,3,3,2,2,2,2,2,2};

__global__ __launch_bounds__(256) void attn_v12(const u16* __restrict__ Qh,
                                                const u16* __restrict__ Kh,
                                                const u16* __restrict__ Vt,
                                                u16* __restrict__ X,
                                                float* __restrict__ Opart,
                                                float* __restrict__ Lpart) {
    __shared__ u16 Ks[2][64 * 64];   // [buf][k-row][64 d]  (8KB/buf)
    __shared__ u16 Vs[2][64 * 64];   // [buf][d-row][64 k]  (8KB/buf)
    __shared__ u16 Ps[4][16 * 64];   // wave-private P [16 q][64 k], swizzled (8KB)
                                     // front 128B/wave reused as lred after loop
    const int tid = threadIdx.x;
    const int w = tid >> 6, lane = tid & 63;
    const int col16 = lane & 15, quad = lane >> 4;
    // XCD-aware swizzle: 1024 = 8 XCD x 128; each XCD owns 4 bh.
    // per-bh slot rotation (+8) spreads unit sizes across CUs.
    const int raw = blockIdx.x;
    const int bsw = (raw & 7) * 128 + (raw >> 3);
    const int bh = bsw >> 5;
    const int slot = ((bsw & 31) + bh * 8) & 31;
    const int tq = STQ[slot];
    const int c0 = SC0[slot];
    const int nc = SNC[slot];
    const int ps = SPS[slot];
    const int q0 = tq * 128 + w * 32;
    const u16* Qp = Qh + (size_t)bh * 2048 * 64;
    const u16* Kp = Kh + (size_t)bh * 2048 * 64;
    const u16* Vp = Vt + (size_t)bh * 64 * VSTRIDE;
    u16* Pw = Ps[w];
    const int swz = (col16 & 7) << 3;      // row-XOR for all LDS tiles (u16 units)

    // Q fragments (used as B-operand of K*Q^T -- identical lane data)
    bf16x8 qa[2][2];
#pragma unroll
    for (int t = 0; t < 2; ++t)
#pragma unroll
        for (int hf = 0; hf < 2; ++hf)
            qa[t][hf] = *(const bf16x8*)&Qp[(size_t)(q0 + t * 16 + col16) * 64 + hf * 32 + quad * 8];

    float l_acc[2] = {0.f, 0.f};
    f32x4 o[2][4];
#pragma unroll
    for (int t = 0; t < 2; ++t)
#pragma unroll
        for (int f = 0; f < 4; ++f) o[t][f] = (f32x4){0.f, 0.f, 0.f, 0.f};

    // staging decomposition: each gld_lds covers 8 rows x 128B; lane = r*8+s.
    // swizzled granule: global slot = s ^ r  (involution; read applies same XOR)
    const int sr = lane >> 3;              // row within instr (0..7)
    const int sg = ((lane & 7) ^ sr) * 8;  // pre-swizzled 16B granule (u16 units)

    // ---- prologue: stage chunk c0 into buf 0 (4 instrs/wave: 2 K + 2 V) ----
    {
        const int k0 = c0 * 64;
#pragma unroll
        for (int i = 0; i < 2; ++i) {
            int c = w * 2 + i;
            gld_lds16(Kp + (size_t)(k0 + c * 8 + sr) * 64 + sg, &Ks[0][c * 512 + lane * 8]);
        }
#pragma unroll
        for (int i = 0; i < 2; ++i) {
            int c = w * 2 + i;
            gld_lds16(Vp + (size_t)(c * 8 + sr) * VSTRIDE + k0 + sg, &Vs[0][c * 512 + lane * 8]);
        }
    }

    for (int ci = 0; ci < nc; ++ci) {
        const int cur = ci & 1;
        const u16* KsC = Ks[cur];
        const u16* VsC = Vs[cur];

        // ---- issue next chunk's stage into the other buffer ----
        if (ci + 1 < nc) {
            const int k0n = (c0 + ci + 1) * 64;
            u16* Kd = Ks[cur ^ 1];
            u16* Vd = Vs[cur ^ 1];
#pragma unroll
            for (int i = 0; i < 2; ++i) {
                int c = w * 2 + i;
                gld_lds16(Kp + (size_t)(k0n + c * 8 + sr) * 64 + sg, Kd + c * 512 + lane * 8);
            }
#pragma unroll
            for (int i = 0; i < 2; ++i) {
                int c = w * 2 + i;
                gld_lds16(Vp + (size_t)(c * 8 + sr) * VSTRIDE + k0n + sg, Vd + c * 512 + lane * 8);
            }
            // wait only for CURRENT chunk's 4 loads; next chunk's 4 stay in flight
            asm volatile("s_waitcnt vmcnt(4)" ::: "memory");
        } else {
            asm volatile("s_waitcnt vmcnt(0)" ::: "memory");
        }
        asm volatile("s_barrier" ::: "memory");

        const int k0 = (c0 + ci) * 64;

        // ---- K*Q^T -> S^T ----
        f32x4 s[2][4];
#pragma unroll
        for (int t = 0; t < 2; ++t)
#pragma unroll
            for (int kt = 0; kt < 4; ++kt) s[t][kt] = (f32x4){0.f, 0.f, 0.f, 0.f};
#pragma unroll
        for (int kt = 0; kt < 4; ++kt) {
            const u16* kb = &KsC[(kt * 16 + col16) * 64];
            bf16x8 kf0 = *(const bf16x8*)&kb[(quad * 8) ^ swz];
            bf16x8 kf1 = *(const bf16x8*)&kb[(32 + quad * 8) ^ swz];
            s[0][kt] = mfma_16x16x32(kf0, qa[0][0], s[0][kt]);
            s[0][kt] = mfma_16x16x32(kf1, qa[0][1], s[0][kt]);
            s[1][kt] = mfma_16x16x32(kf0, qa[1][0], s[1][kt]);
            s[1][kt] = mfma_16x16x32(kf1, qa[1][1], s[1][kt]);
        }

        const bool domask = (k0 + 63 > q0);

        // ---- t = 0: softmax -> P tile -> PV (vf from LDS) ----
        {
            const int qg = q0 + col16;
            float rs = 0.f;
#pragma unroll
            for (int kt = 0; kt < 4; ++kt) {
                float p[4];
#pragma unroll
                for (int r = 0; r < 4; ++r) {
                    float sv = s[0][kt][r];
                    if (domask && (k0 + kt * 16 + quad * 4 + r > qg)) sv = -1e30f;
                    p[r] = __builtin_amdgcn_exp2f(sv - FIXED_M2);
                    rs += p[r];
                }
                unsigned* prow = (unsigned*)&Pw[col16 * 64 + ((kt * 16 + quad * 4) ^ swz)];
                prow[0] = pk2(p[0], p[1]);
                prow[1] = pk2(p[2], p[3]);
            }
            l_acc[0] += rs;
        }
        asm volatile("s_waitcnt lgkmcnt(0)" ::: "memory");  // P writes -> reads
#pragma unroll
        for (int ss = 0; ss < 2; ++ss) {
            const int ko = (ss * 32 + quad * 8) ^ swz;
            bf16x8 pf = *(const bf16x8*)&Pw[col16 * 64 + ko];
#pragma unroll
            for (int f = 0; f < 4; ++f) {
                bf16x8 vf = *(const bf16x8*)&VsC[(f * 16 + col16) * 64 + ko];
                o[0][f] = mfma_16x16x32(pf, vf, o[0][f]);
            }
        }

        // ---- t = 1: softmax -> P tile (overwrite; same-wave DS in-order) ----
        {
            const int qg = q0 + 16 + col16;
            float rs = 0.f;
#pragma unroll
            for (int kt = 0; kt < 4; ++kt) {
                float p[4];
#pragma unroll
                for (int r = 0; r < 4; ++r) {
                    float sv = s[1][kt][r];
                    if (domask && (k0 + kt * 16 + quad * 4 + r > qg)) sv = -1e30f;
                    p[r] = __builtin_amdgcn_exp2f(sv - FIXED_M2);
                    rs += p[r];
                }
                unsigned* prow = (unsigned*)&Pw[col16 * 64 + ((kt * 16 + quad * 4) ^ swz)];
                prow[0] = pk2(p[0], p[1]);
                prow[1] = pk2(p[2], p[3]);
            }
            l_acc[1] += rs;
        }
        asm volatile("s_waitcnt lgkmcnt(0)" ::: "memory");  // P writes -> reads
#pragma unroll
        for (int ss = 0; ss < 2; ++ss) {
            const int ko = (ss * 32 + quad * 8) ^ swz;
            bf16x8 pf = *(const bf16x8*)&Pw[col16 * 64 + ko];
#pragma unroll
            for (int f = 0; f < 4; ++f) {
                bf16x8 vf = *(const bf16x8*)&VsC[(f * 16 + col16) * 64 + ko];
                o[1][f] = mfma_16x16x32(pf, vf, o[1][f]);
            }
        }

        // all LDS reads of buf[cur] complete before next iteration's stage
        asm volatile("s_waitcnt lgkmcnt(0)" ::: "memory");
        asm volatile("s_barrier" ::: "memory");
    }

    // ---- l reduction across quads (butterfly -> every lane has row total) ----
    float* lredw = (float*)Pw;   // alias: P tile dead after loop
    float lt[2];
#pragma unroll
    for (int t = 0; t < 2; ++t) {
        float l = l_acc[t];
        l += __shfl_xor(l, 16);
        l += __shfl_xor(l, 32);
        lt[t] = l;
        if (quad == 0) lredw[t * 16 + col16] = l;
    }
    asm volatile("s_waitcnt lgkmcnt(0)" ::: "memory");

    if (ps >= 0) {
        // ---- partial epilogue: raw O (no divide) + l to workspace ----
        const int pg = bh * 27 + ps;
        float* Op = Opart + ((size_t)pg * 128 + w * 32) * 64;
#pragma unroll
        for (int t = 0; t < 2; ++t) {
#pragma unroll
            for (int r = 0; r < 4; ++r) {
                float* Crow = Op + (t * 16 + quad * 4 + r) * 64;
#pragma unroll
                for (int f = 0; f < 4; ++f)
                    Crow[f * 16 + col16] = o[t][f][r];
            }
        }
        if (quad == 0) {
            float* Lp = Lpart + (size_t)pg * 128 + w * 32;
#pragma unroll
            for (int t = 0; t < 2; ++t) Lp[t * 16 + col16] = lt[t];
        }
        return;
    }

    // ---- direct epilogue (single-unit tile): divide and write X ----
    const int b = bh >> 4, h = bh & 15;
#pragma unroll
    for (int t = 0; t < 2; ++t) {
#pragma unroll
        for (int r = 0; r < 4; ++r) {
            float inv = 1.0f / lredw[t * 16 + quad * 4 + r];
            int srow = q0 + t * 16 + quad * 4 + r;
            u16* Xp = X + ((size_t)(b * 2048 + srow)) * 1024 + h * 64;
#pragma unroll
            for (int f = 0; f < 4; ++f)
                Xp[f * 16 + col16] = f2b(o[t][f][r] * inv);
        }
    }
}

// ---------------------------------------------------------------------------
// attn_reduce: combine 2-3 partials per (bh, tq in 5..15): X = (sum O)/(sum l)
// ---------------------------------------------------------------------------
__global__ __launch_bounds__(256) void attn_reduce(const float* __restrict__ Opart,
                                                   const float* __restrict__ Lpart,
                                                   u16* __restrict__ X) {
    const int bh = blockIdx.x;           // 0..31
    const int ti = blockIdx.y;           // 0..10
    const int tq = RTQ[ti];
    const int np = RN[ti];
    const int base = bh * 27 + RB[ti];
    const int tid = threadIdx.x;
    const int b = bh >> 4, h = bh & 15;
#pragma unroll
    for (int i = 0; i < 8; ++i) {
        int e4 = i * 256 + tid;          // float4 index within 128x64 tile
        int q = e4 >> 4, d0 = (e4 & 15) * 4;
        float4 a = ((const float4*)Opart)[(size_t)base * 2048 + e4];
        float l = Lpart[(size_t)base * 128 + q];
        for (int u = 1; u < np; ++u) {
            float4 c = ((const float4*)Opart)[(size_t)(base + u) * 2048 + e4];
            a.x += c.x; a.y += c.y; a.z += c.z; a.w += c.w;
            l += Lpart[(size_t)(base + u) * 128 + q];
        }
        float inv = 1.0f / l;
        ushort4 ov;
        ov.x = f2b(a.x * inv); ov.y = f2b(a.y * inv);
        ov.z = f2b(a.z * inv); ov.w = f2b(a.w * inv);
        *(ushort4*)&X[((size_t)(b * 2048 + tq * 128 + q)) * 1024 + h * 64 + d0] = ov;
    }
}

// ---------------------------------------------------------------------------
// launch
// ---------------------------------------------------------------------------
extern "C" void kernel_launch(void* const* d_in, const int* in_sizes, int n_in,
                              void* d_out, int out_size, void* d_ws, size_t ws_size,
                              hipStream_t stream) {
    const float* inputs = (const float*)d_in[0];
    const int* segpos   = (const int*)d_in[1];
    const float* W_in   = (const float*)d_in[3];
    const float* W_out  = (const float*)d_in[4];
    float* out = (float*)d_out;

    u16* ws = (u16*)d_ws;
    u16* qkv   = ws;                               // 4096*3072 bf16
    u16* x     = qkv;                              // alias (qkv dead after rope_vt)
    u16* inB   = qkv + 12582912 + 512;
    u16* WtB   = inB + 4194304 + 512;              // W_in^T  [3072][1024]
    u16* WotB  = WtB + 3145728 + 512;              // W_out^T [1024][1024]
    u16* Qh    = WotB + 1048576 + 512;             // [BH][S][64]
    u16* Kh    = Qh + 4194304 + 512;
    u16* Vt    = Kh + 4194304 + 512;               // [BH][64][VSTRIDE]
    // split-K partials: region [X_end, WotB) is dead during attn.
    // X = 4.19M u16; Opart: 864 slots x 128 x 64 f32 = 14,155,776 u16;
    // Lpart: 864 x 128 f32 = 221,184 u16; end = 18,571,776 < 19,924,480. OK.
    float* Opart = (float*)(ws + 4194816);
    float* Lpart = (float*)(ws + 4194816 + 14155776);

    prep<<<dim3(8192), 256, 0, stream>>>(inputs, inB, W_in, WtB, W_out, WotB);
    gemm_tn<false><<<dim3(24, 32), 256, 0, stream>>>(inB, WtB, qkv, 4096, 3072, 1024);
    rope_vt<<<dim3(3072), 256, 0, stream>>>(qkv, segpos, Qh, Kh, Vt);
    attn_v12<<<dim3(1024), 256, 0, stream>>>(Qh, Kh, Vt, x, Opart, Lpart);
    attn_reduce<<<dim3(32, 11), 256, 0, stream>>>(Opart, Lpart, x);
    gemm_tn<true><<<dim3(8, 32), 256, 0, stream>>>(x, WotB, out, 4096, 1024, 1024);
}